// Round 1
// baseline (1365.462 us; speedup 1.0000x reference)
//
#include <hip/hip_runtime.h>
#include <hip/hip_bf16.h>

#define IN_DIM 128
#define HDIM 128   // H*D for layers 1-2

// ---------------- CSR build ----------------

__global__ __launch_bounds__(256) void hist_kernel(const int* __restrict__ dst,
                                                   int* __restrict__ deg, int E) {
  int e = blockIdx.x * 256 + threadIdx.x;
  if (e < E) atomicAdd(&deg[dst[e]], 1);
}

__global__ __launch_bounds__(512) void scan1_kernel(const int* __restrict__ deg,
                                                    int* __restrict__ partial,
                                                    int* __restrict__ bsum, int n) {
  __shared__ int sm[512];
  int g = blockIdx.x * 512 + threadIdx.x;
  int v = (g < n) ? deg[g] : 0;
  sm[threadIdx.x] = v;
  __syncthreads();
  for (int off = 1; off < 512; off <<= 1) {
    int t = (threadIdx.x >= off) ? sm[threadIdx.x - off] : 0;
    __syncthreads();
    sm[threadIdx.x] += t;
    __syncthreads();
  }
  if (g < n) partial[g] = sm[threadIdx.x];
  if (threadIdx.x == 511) bsum[blockIdx.x] = sm[511];
}

__global__ __launch_bounds__(512) void scan2_kernel(int* __restrict__ bsum, int nblk) {
  __shared__ int sm[512];
  int v = (threadIdx.x < nblk) ? bsum[threadIdx.x] : 0;
  sm[threadIdx.x] = v;
  __syncthreads();
  for (int off = 1; off < 512; off <<= 1) {
    int t = (threadIdx.x >= off) ? sm[threadIdx.x - off] : 0;
    __syncthreads();
    sm[threadIdx.x] += t;
    __syncthreads();
  }
  if (threadIdx.x < nblk) bsum[threadIdx.x] = sm[threadIdx.x];
}

__global__ __launch_bounds__(512) void scanfix_kernel(const int* __restrict__ partial,
                                                      const int* __restrict__ bsum,
                                                      const int* __restrict__ deg,
                                                      int* __restrict__ row_ptr,
                                                      int* __restrict__ cursor, int n) {
  int g = blockIdx.x * 512 + threadIdx.x;
  if (g >= n) return;
  int off = (blockIdx.x > 0) ? bsum[blockIdx.x - 1] : 0;
  int incl = partial[g] + off;
  row_ptr[g + 1] = incl;
  cursor[g] = incl - deg[g];
  if (g == 0) row_ptr[0] = 0;
}

__global__ __launch_bounds__(256) void scatter_kernel(const int* __restrict__ src,
                                                      const int* __restrict__ dst,
                                                      int* __restrict__ cursor,
                                                      int* __restrict__ col, int E) {
  int e = blockIdx.x * 256 + threadIdx.x;
  if (e >= E) return;
  int d = dst[e];
  int p = atomicAdd(&cursor[d], 1);
  col[p] = src[e];
}

// ---------------- GEMMs (fp32 vector) ----------------

// X:[n,128] @ W:[128,128] -> F:[n,128]. BM=128 rows/block, 256 thr, 8x8 micro.
__global__ __launch_bounds__(256) void gemm128_kernel(const float* __restrict__ X,
                                                      const float* __restrict__ W,
                                                      float* __restrict__ Fout, int n) {
  __shared__ float As[16][132];  // [k][m], padded (132*4=528 bytes, 16B aligned rows)
  __shared__ float Bs[16][128];  // [k][nn]
  const int tid = threadIdx.x;
  const int tm = tid >> 4, tn = tid & 15;
  const int bm = blockIdx.x * 128;
  float acc[8][8];
#pragma unroll
  for (int i = 0; i < 8; ++i)
#pragma unroll
    for (int j = 0; j < 8; ++j) acc[i][j] = 0.f;

  for (int kc = 0; kc < 128; kc += 16) {
#pragma unroll
    for (int jj = 0; jj < 2; ++jj) {
      int rl = (tid >> 2) + jj * 64;
      int c4 = (tid & 3) * 4;
      int row = bm + rl;
      float4 v = make_float4(0.f, 0.f, 0.f, 0.f);
      if (row < n) v = *(const float4*)&X[(size_t)row * IN_DIM + kc + c4];
      As[c4 + 0][rl] = v.x; As[c4 + 1][rl] = v.y;
      As[c4 + 2][rl] = v.z; As[c4 + 3][rl] = v.w;
    }
#pragma unroll
    for (int jj = 0; jj < 2; ++jj) {
      int idx = tid + jj * 256;
      int kr = idx >> 5;
      int c4 = (idx & 31) * 4;
      *(float4*)&Bs[kr][c4] = *(const float4*)&W[(size_t)(kc + kr) * HDIM + c4];
    }
    __syncthreads();
#pragma unroll
    for (int k = 0; k < 16; ++k) {
      float4 a0 = *(const float4*)&As[k][tm * 8];
      float4 a1 = *(const float4*)&As[k][tm * 8 + 4];
      float4 b0 = *(const float4*)&Bs[k][tn * 8];
      float4 b1 = *(const float4*)&Bs[k][tn * 8 + 4];
      float av[8] = {a0.x, a0.y, a0.z, a0.w, a1.x, a1.y, a1.z, a1.w};
      float bv[8] = {b0.x, b0.y, b0.z, b0.w, b1.x, b1.y, b1.z, b1.w};
#pragma unroll
      for (int i = 0; i < 8; ++i)
#pragma unroll
        for (int j = 0; j < 8; ++j) acc[i][j] = fmaf(av[i], bv[j], acc[i][j]);
    }
    __syncthreads();
  }
#pragma unroll
  for (int i = 0; i < 8; ++i) {
    int row = bm + tm * 8 + i;
    if (row < n) {
      float4 v0 = make_float4(acc[i][0], acc[i][1], acc[i][2], acc[i][3]);
      float4 v1 = make_float4(acc[i][4], acc[i][5], acc[i][6], acc[i][7]);
      *(float4*)&Fout[(size_t)row * HDIM + tn * 8] = v0;
      *(float4*)&Fout[(size_t)row * HDIM + tn * 8 + 4] = v1;
    }
  }
}

// X:[n,128] @ W:[128,32] -> F:[n,32]. 32 rows/block, thread = (row, 4 cols).
__global__ __launch_bounds__(256) void gemm_n32_kernel(const float* __restrict__ X,
                                                       const float* __restrict__ W,
                                                       float* __restrict__ Fout, int n) {
  __shared__ float Xs[32][132];
  __shared__ float Ws[128][32];
  const int tid = threadIdx.x;
  const int row0 = blockIdx.x * 32;
#pragma unroll
  for (int jj = 0; jj < 4; ++jj) {
    int idx = tid + jj * 256;   // float4 index over 128x32
    int r = idx >> 3;
    int c4 = (idx & 7) * 4;
    *(float4*)&Ws[r][c4] = *(const float4*)&W[(size_t)r * 32 + c4];
  }
#pragma unroll
  for (int jj = 0; jj < 4; ++jj) {
    int idx = tid + jj * 256;   // float4 index over 32x128
    int r = idx >> 5;
    int c4 = (idx & 31) * 4;
    int row = row0 + r;
    float4 v = make_float4(0.f, 0.f, 0.f, 0.f);
    if (row < n) v = *(const float4*)&X[(size_t)row * HDIM + c4];
    *(float4*)&Xs[r][c4] = v;
  }
  __syncthreads();
  const int r = tid >> 3, cg = (tid & 7) * 4;
  float4 acc = make_float4(0.f, 0.f, 0.f, 0.f);
#pragma unroll 8
  for (int k = 0; k < 128; ++k) {
    float a = Xs[r][k];
    float4 b = *(const float4*)&Ws[k][cg];
    acc.x = fmaf(a, b.x, acc.x); acc.y = fmaf(a, b.y, acc.y);
    acc.z = fmaf(a, b.z, acc.z); acc.w = fmaf(a, b.w, acc.w);
  }
  int row = row0 + r;
  if (row < n) *(float4*)&Fout[(size_t)row * 32 + cg] = acc;
}

// ---------------- el/er dot products ----------------

template <int H, int D>
__global__ __launch_bounds__(256) void el_er_kernel(const float* __restrict__ f,
                                                    const float* __restrict__ al,
                                                    const float* __restrict__ ar,
                                                    float* __restrict__ el,
                                                    float* __restrict__ er, int n) {
  int gid = (blockIdx.x * 256 + threadIdx.x) >> 5;  // one 32-lane group per (node,head)
  int lane = threadIdx.x & 31;
  if (gid >= n * H) return;
  int node = gid / H, h = gid % H;
  float fv = f[(size_t)(node * H + h) * D + lane];
  float vl = fv * al[h * D + lane];
  float vr = fv * ar[h * D + lane];
#pragma unroll
  for (int o = 16; o >= 1; o >>= 1) {
    vl += __shfl_xor(vl, o);
    vr += __shfl_xor(vr, o);
  }
  if (lane == 0) { el[gid] = vl; er[gid] = vr; }
}

// ---------------- segment softmax + aggregation (node-parallel, CSR) ----------------

template <int H, int D, bool ELU>
__global__ __launch_bounds__(256) void aggregate_kernel(const float* __restrict__ f,
                                                        const float* __restrict__ el,
                                                        const float* __restrict__ er,
                                                        const float* __restrict__ bias,
                                                        const int* __restrict__ row_ptr,
                                                        const int* __restrict__ col,
                                                        float* __restrict__ out, int n) {
  constexpr int F = H * D;          // 128 or 32
  constexpr int LPN = F / 2;        // lanes per node
  constexpr int NPB = 256 / LPN;    // nodes per block
  int node = blockIdx.x * NPB + threadIdx.x / LPN;
  int ll = threadIdx.x % LPN;
  if (node >= n) return;
  int h = (2 * ll) / D;
  float er_n = er[node * H + h];
  int beg = row_ptr[node], end = row_ptr[node + 1];

  float m = -3.0e38f;
  for (int i = beg; i < end; ++i) {
    int s = col[i];
    float e = el[s * H + h] + er_n;
    e = (e > 0.f) ? e : 0.2f * e;
    m = fmaxf(m, e);
  }
  if (beg == end) m = 0.f;  // zero in-degree safety (matches isfinite->0)

  float ssum = 0.f;
  for (int i = beg; i < end; ++i) {
    int s = col[i];
    float e = el[s * H + h] + er_n;
    e = (e > 0.f) ? e : 0.2f * e;
    ssum += __expf(e - m);
  }
  float inv = 1.f / fmaxf(ssum, 1e-9f);

  float a0 = 0.f, a1 = 0.f;
  for (int i = beg; i < end; ++i) {
    int s = col[i];
    float e = el[s * H + h] + er_n;
    e = (e > 0.f) ? e : 0.2f * e;
    float wgt = __expf(e - m) * inv;
    float2 fv = *(const float2*)&f[(size_t)s * F + 2 * ll];
    a0 = fmaf(wgt, fv.x, a0);
    a1 = fmaf(wgt, fv.y, a1);
  }
  float o0 = a0 + bias[2 * ll];
  float o1 = a1 + bias[2 * ll + 1];
  if (ELU) {
    o0 = (o0 > 0.f) ? o0 : (__expf(o0) - 1.f);
    o1 = (o1 > 0.f) ? o1 : (__expf(o1) - 1.f);
  }
  *(float2*)&out[(size_t)node * F + 2 * ll] = make_float2(o0, o1);
}

// ---------------- launcher ----------------

extern "C" void kernel_launch(void* const* d_in, const int* in_sizes, int n_in,
                              void* d_out, int out_size, void* d_ws, size_t ws_size,
                              hipStream_t stream) {
  const float* x   = (const float*)d_in[0];
  const int*   src = (const int*)d_in[1];
  const int*   dst = (const int*)d_in[2];
  const float* W1  = (const float*)d_in[3];
  const float* al1 = (const float*)d_in[4];
  const float* ar1 = (const float*)d_in[5];
  const float* b1  = (const float*)d_in[6];
  const float* W2  = (const float*)d_in[7];
  const float* al2 = (const float*)d_in[8];
  const float* ar2 = (const float*)d_in[9];
  const float* b2  = (const float*)d_in[10];
  const float* W3  = (const float*)d_in[11];
  const float* al3 = (const float*)d_in[12];
  const float* ar3 = (const float*)d_in[13];
  const float* b3  = (const float*)d_in[14];
  float* out = (float*)d_out;

  const int N = in_sizes[0] / IN_DIM;   // 100000
  const int E = in_sizes[1];            // 1600000

  char* w = (char*)d_ws;
  size_t off = 0;
  auto alloc = [&](size_t bytes) -> void* {
    void* p = w + off;
    off += (bytes + 255) & ~(size_t)255;
    return p;
  };
  int*   deg     = (int*)alloc((size_t)N * 4);
  int*   row_ptr = (int*)alloc((size_t)(N + 1) * 4);
  int*   cursor  = (int*)alloc((size_t)N * 4);
  int*   bsum    = (int*)alloc(4096);
  int*   col     = (int*)alloc((size_t)E * 4);
  float* el      = (float*)alloc((size_t)N * 4 * 4);
  float* er      = (float*)alloc((size_t)N * 4 * 4);
  float* bufA    = (float*)alloc((size_t)N * 128 * 4);
  float* bufB    = (float*)alloc((size_t)N * 128 * 4);

  // ---- CSR build (graph shared by all 3 layers) ----
  hipMemsetAsync(deg, 0, (size_t)N * 4, stream);
  hist_kernel<<<(E + 255) / 256, 256, 0, stream>>>(dst, deg, E);
  int nblk = (N + 511) / 512;
  scan1_kernel<<<nblk, 512, 0, stream>>>(deg, cursor, bsum, N);
  scan2_kernel<<<1, 512, 0, stream>>>(bsum, nblk);
  scanfix_kernel<<<nblk, 512, 0, stream>>>(cursor, bsum, deg, row_ptr, cursor, N);
  scatter_kernel<<<(E + 255) / 256, 256, 0, stream>>>(src, dst, cursor, col, E);

  const int gb = (N + 127) / 128;
  // ---- layer 1 ----
  gemm128_kernel<<<gb, 256, 0, stream>>>(x, W1, bufA, N);
  el_er_kernel<4, 32><<<(N * 4 + 7) / 8, 256, 0, stream>>>(bufA, al1, ar1, el, er, N);
  aggregate_kernel<4, 32, true><<<(N + 3) / 4, 256, 0, stream>>>(bufA, el, er, b1, row_ptr, col, bufB, N);
  // ---- layer 2 ----
  gemm128_kernel<<<gb, 256, 0, stream>>>(bufB, W2, bufA, N);
  el_er_kernel<4, 32><<<(N * 4 + 7) / 8, 256, 0, stream>>>(bufA, al2, ar2, el, er, N);
  aggregate_kernel<4, 32, true><<<(N + 3) / 4, 256, 0, stream>>>(bufA, el, er, b2, row_ptr, col, bufB, N);
  // ---- layer 3 ----
  gemm_n32_kernel<<<(N + 31) / 32, 256, 0, stream>>>(bufB, W3, bufA, N);
  el_er_kernel<1, 32><<<(N + 7) / 8, 256, 0, stream>>>(bufA, al3, ar3, el, er, N);
  aggregate_kernel<1, 32, false><<<(N + 15) / 16, 256, 0, stream>>>(bufA, el, er, b3, row_ptr, col, out, N);
}

// Round 5
// 788.344 us; speedup vs baseline: 1.7321x; 1.7321x over previous
//
#include <hip/hip_runtime.h>
#include <hip/hip_bf16.h>

#define IN_DIM 128
#define HDIM 128   // H*D for layers 1-2

// ---------------- CSR build ----------------

__global__ __launch_bounds__(256) void hist_kernel(const int* __restrict__ dst,
                                                   int* __restrict__ deg, int E) {
  int e = blockIdx.x * 256 + threadIdx.x;
  if (e < E) atomicAdd(&deg[dst[e]], 1);
}

__global__ __launch_bounds__(512) void scan1_kernel(const int* __restrict__ deg,
                                                    int* __restrict__ partial,
                                                    int* __restrict__ bsum, int n) {
  __shared__ int sm[512];
  int g = blockIdx.x * 512 + threadIdx.x;
  int v = (g < n) ? deg[g] : 0;
  sm[threadIdx.x] = v;
  __syncthreads();
  for (int off = 1; off < 512; off <<= 1) {
    int t = (threadIdx.x >= off) ? sm[threadIdx.x - off] : 0;
    __syncthreads();
    sm[threadIdx.x] += t;
    __syncthreads();
  }
  if (g < n) partial[g] = sm[threadIdx.x];
  if (threadIdx.x == 511) bsum[blockIdx.x] = sm[511];
}

__global__ __launch_bounds__(512) void scan2_kernel(int* __restrict__ bsum, int nblk) {
  __shared__ int sm[512];
  int v = (threadIdx.x < nblk) ? bsum[threadIdx.x] : 0;
  sm[threadIdx.x] = v;
  __syncthreads();
  for (int off = 1; off < 512; off <<= 1) {
    int t = (threadIdx.x >= off) ? sm[threadIdx.x - off] : 0;
    __syncthreads();
    sm[threadIdx.x] += t;
    __syncthreads();
  }
  if (threadIdx.x < nblk) bsum[threadIdx.x] = sm[threadIdx.x];
}

__global__ __launch_bounds__(512) void scanfix_kernel(const int* __restrict__ partial,
                                                      const int* __restrict__ bsum,
                                                      const int* __restrict__ deg,
                                                      int* __restrict__ row_ptr,
                                                      int* __restrict__ cursor, int n) {
  int g = blockIdx.x * 512 + threadIdx.x;
  if (g >= n) return;
  int off = (blockIdx.x > 0) ? bsum[blockIdx.x - 1] : 0;
  int incl = partial[g] + off;
  row_ptr[g + 1] = incl;
  cursor[g] = incl - deg[g];
  if (g == 0) row_ptr[0] = 0;
}

__global__ __launch_bounds__(256) void scatter_kernel(const int* __restrict__ src,
                                                      const int* __restrict__ dst,
                                                      int* __restrict__ cursor,
                                                      int* __restrict__ col, int E) {
  int e = blockIdx.x * 256 + threadIdx.x;
  if (e >= E) return;
  int d = dst[e];
  int p = atomicAdd(&cursor[d], 1);
  col[p] = src[e];
}

// ---------------- GEMMs (fp32 vector) ----------------

// X:[n,128] @ W:[128,128] -> F:[n,128]. BM=128 rows/block, 256 thr, 8x8 micro.
__global__ __launch_bounds__(256) void gemm128_kernel(const float* __restrict__ X,
                                                      const float* __restrict__ W,
                                                      float* __restrict__ Fout, int n) {
  __shared__ float As[16][132];
  __shared__ float Bs[16][128];
  const int tid = threadIdx.x;
  const int tm = tid >> 4, tn = tid & 15;
  const int bm = blockIdx.x * 128;
  float acc[8][8];
#pragma unroll
  for (int i = 0; i < 8; ++i)
#pragma unroll
    for (int j = 0; j < 8; ++j) acc[i][j] = 0.f;

  for (int kc = 0; kc < 128; kc += 16) {
#pragma unroll
    for (int jj = 0; jj < 2; ++jj) {
      int rl = (tid >> 2) + jj * 64;
      int c4 = (tid & 3) * 4;
      int row = bm + rl;
      float4 v = make_float4(0.f, 0.f, 0.f, 0.f);
      if (row < n) v = *(const float4*)&X[(size_t)row * IN_DIM + kc + c4];
      As[c4 + 0][rl] = v.x; As[c4 + 1][rl] = v.y;
      As[c4 + 2][rl] = v.z; As[c4 + 3][rl] = v.w;
    }
#pragma unroll
    for (int jj = 0; jj < 2; ++jj) {
      int idx = tid + jj * 256;
      int kr = idx >> 5;
      int c4 = (idx & 31) * 4;
      *(float4*)&Bs[kr][c4] = *(const float4*)&W[(size_t)(kc + kr) * HDIM + c4];
    }
    __syncthreads();
#pragma unroll
    for (int k = 0; k < 16; ++k) {
      float4 a0 = *(const float4*)&As[k][tm * 8];
      float4 a1 = *(const float4*)&As[k][tm * 8 + 4];
      float4 b0 = *(const float4*)&Bs[k][tn * 8];
      float4 b1 = *(const float4*)&Bs[k][tn * 8 + 4];
      float av[8] = {a0.x, a0.y, a0.z, a0.w, a1.x, a1.y, a1.z, a1.w};
      float bv[8] = {b0.x, b0.y, b0.z, b0.w, b1.x, b1.y, b1.z, b1.w};
#pragma unroll
      for (int i = 0; i < 8; ++i)
#pragma unroll
        for (int j = 0; j < 8; ++j) acc[i][j] = fmaf(av[i], bv[j], acc[i][j]);
    }
    __syncthreads();
  }
#pragma unroll
  for (int i = 0; i < 8; ++i) {
    int row = bm + tm * 8 + i;
    if (row < n) {
      float4 v0 = make_float4(acc[i][0], acc[i][1], acc[i][2], acc[i][3]);
      float4 v1 = make_float4(acc[i][4], acc[i][5], acc[i][6], acc[i][7]);
      *(float4*)&Fout[(size_t)row * HDIM + tn * 8] = v0;
      *(float4*)&Fout[(size_t)row * HDIM + tn * 8 + 4] = v1;
    }
  }
}

// X:[n,128] @ W:[128,32] -> F:[n,32]. 32 rows/block, thread = (row, 4 cols).
__global__ __launch_bounds__(256) void gemm_n32_kernel(const float* __restrict__ X,
                                                       const float* __restrict__ W,
                                                       float* __restrict__ Fout, int n) {
  __shared__ float Xs[32][132];
  __shared__ float Ws[128][32];
  const int tid = threadIdx.x;
  const int row0 = blockIdx.x * 32;
#pragma unroll
  for (int jj = 0; jj < 4; ++jj) {
    int idx = tid + jj * 256;
    int r = idx >> 3;
    int c4 = (idx & 7) * 4;
    *(float4*)&Ws[r][c4] = *(const float4*)&W[(size_t)r * 32 + c4];
  }
#pragma unroll
  for (int jj = 0; jj < 4; ++jj) {
    int idx = tid + jj * 256;
    int r = idx >> 5;
    int c4 = (idx & 31) * 4;
    int row = row0 + r;
    float4 v = make_float4(0.f, 0.f, 0.f, 0.f);
    if (row < n) v = *(const float4*)&X[(size_t)row * HDIM + c4];
    *(float4*)&Xs[r][c4] = v;
  }
  __syncthreads();
  const int r = tid >> 3, cg = (tid & 7) * 4;
  float4 acc = make_float4(0.f, 0.f, 0.f, 0.f);
#pragma unroll 8
  for (int k = 0; k < 128; ++k) {
    float a = Xs[r][k];
    float4 b = *(const float4*)&Ws[k][cg];
    acc.x = fmaf(a, b.x, acc.x); acc.y = fmaf(a, b.y, acc.y);
    acc.z = fmaf(a, b.z, acc.z); acc.w = fmaf(a, b.w, acc.w);
  }
  int row = row0 + r;
  if (row < n) *(float4*)&Fout[(size_t)row * 32 + cg] = acc;
}

// ---------------- el/er dot products ----------------

template <int H, int D>
__global__ __launch_bounds__(256) void el_er_kernel(const float* __restrict__ f,
                                                    const float* __restrict__ al,
                                                    const float* __restrict__ ar,
                                                    float* __restrict__ el,
                                                    float* __restrict__ er, int n) {
  int gid = (blockIdx.x * 256 + threadIdx.x) >> 5;
  int lane = threadIdx.x & 31;
  if (gid >= n * H) return;
  int node = gid / H, h = gid % H;
  float fv = f[(size_t)(node * H + h) * D + lane];
  float vl = fv * al[h * D + lane];
  float vr = fv * ar[h * D + lane];
#pragma unroll
  for (int o = 16; o >= 1; o >>= 1) {
    vl += __shfl_xor(vl, o);
    vr += __shfl_xor(vr, o);
  }
  if (lane == 0) { el[gid] = vl; er[gid] = vr; }
}

// ---------------- fused single-pass online-softmax aggregation ----------------

template <int H, int D, bool ELU>
__global__ __launch_bounds__(256) void aggregate_kernel(const float* __restrict__ f,
                                                        const float* __restrict__ el,
                                                        const float* __restrict__ er,
                                                        const float* __restrict__ bias,
                                                        const int* __restrict__ row_ptr,
                                                        const int* __restrict__ col,
                                                        float* __restrict__ out, int n) {
  constexpr int F = H * D;          // 128 or 32
  constexpr int LPN = F / 2;        // lanes per node
  constexpr int NPB = 256 / LPN;    // nodes per block
  int node = blockIdx.x * NPB + threadIdx.x / LPN;
  int ll = threadIdx.x % LPN;
  if (node >= n) return;
  const int h = (2 * ll) / D;
  const float er_n = er[node * H + h];
  int beg = row_ptr[node], end = row_ptr[node + 1];

  float m = -3.0e38f, ssum = 0.f, a0 = 0.f, a1 = 0.f;

  constexpr int U = 8;
  int i = beg;
  for (; i + U <= end; i += U) {
    // batched independent loads: break the col->el/f dependence chains
    int s[U];
#pragma unroll
    for (int j = 0; j < U; ++j) s[j] = col[i + j];
    float ev[U];
#pragma unroll
    for (int j = 0; j < U; ++j) {
      float e = el[s[j] * H + h] + er_n;
      ev[j] = (e > 0.f) ? e : 0.2f * e;
    }
    float2 fv[U];
#pragma unroll
    for (int j = 0; j < U; ++j) fv[j] = *(const float2*)&f[(size_t)s[j] * F + 2 * ll];
    float bm = ev[0];
#pragma unroll
    for (int j = 1; j < U; ++j) bm = fmaxf(bm, ev[j]);
    float mnew = fmaxf(m, bm);
    float scale = __expf(m - mnew);   // 0 on first block (m=-3e38), 1 if max unchanged
    ssum *= scale; a0 *= scale; a1 *= scale;
    m = mnew;
#pragma unroll
    for (int j = 0; j < U; ++j) {
      float w = __expf(ev[j] - m);
      ssum += w;
      a0 = fmaf(w, fv[j].x, a0);
      a1 = fmaf(w, fv[j].y, a1);
    }
  }
  for (; i < end; ++i) {
    int s = col[i];
    float e = el[s * H + h] + er_n;
    e = (e > 0.f) ? e : 0.2f * e;
    float mnew = fmaxf(m, e);
    float scale = __expf(m - mnew);
    float w = __expf(e - mnew);
    float2 fv = *(const float2*)&f[(size_t)s * F + 2 * ll];
    ssum = ssum * scale + w;
    a0 = fmaf(w, fv.x, a0 * scale);
    a1 = fmaf(w, fv.y, a1 * scale);
    m = mnew;
  }

  float inv = 1.f / fmaxf(ssum, 1e-9f);
  float o0 = a0 * inv + bias[2 * ll];
  float o1 = a1 * inv + bias[2 * ll + 1];
  if (ELU) {
    o0 = (o0 > 0.f) ? o0 : (__expf(o0) - 1.f);
    o1 = (o1 > 0.f) ? o1 : (__expf(o1) - 1.f);
  }
  *(float2*)&out[(size_t)node * F + 2 * ll] = make_float2(o0, o1);
}

// ---------------- launcher ----------------

extern "C" void kernel_launch(void* const* d_in, const int* in_sizes, int n_in,
                              void* d_out, int out_size, void* d_ws, size_t ws_size,
                              hipStream_t stream) {
  const float* x   = (const float*)d_in[0];
  const int*   src = (const int*)d_in[1];
  const int*   dst = (const int*)d_in[2];
  const float* W1  = (const float*)d_in[3];
  const float* al1 = (const float*)d_in[4];
  const float* ar1 = (const float*)d_in[5];
  const float* b1  = (const float*)d_in[6];
  const float* W2  = (const float*)d_in[7];
  const float* al2 = (const float*)d_in[8];
  const float* ar2 = (const float*)d_in[9];
  const float* b2  = (const float*)d_in[10];
  const float* W3  = (const float*)d_in[11];
  const float* al3 = (const float*)d_in[12];
  const float* ar3 = (const float*)d_in[13];
  const float* b3  = (const float*)d_in[14];
  float* out = (float*)d_out;

  const int N = in_sizes[0] / IN_DIM;   // 100000
  const int E = in_sizes[1];            // 1600000

  char* w = (char*)d_ws;
  size_t off = 0;
  auto alloc = [&](size_t bytes) -> void* {
    void* p = w + off;
    off += (bytes + 255) & ~(size_t)255;
    return p;
  };
  int*   deg     = (int*)alloc((size_t)N * 4);
  int*   row_ptr = (int*)alloc((size_t)(N + 1) * 4);
  int*   cursor  = (int*)alloc((size_t)N * 4);
  int*   bsum    = (int*)alloc(4096);
  int*   col     = (int*)alloc((size_t)E * 4);
  float* el      = (float*)alloc((size_t)N * 4 * 4);
  float* er      = (float*)alloc((size_t)N * 4 * 4);
  float* bufA    = (float*)alloc((size_t)N * 128 * 4);
  float* bufB    = (float*)alloc((size_t)N * 128 * 4);

  // ---- CSR build (graph shared by all 3 layers) ----
  hipMemsetAsync(deg, 0, (size_t)N * 4, stream);
  hist_kernel<<<(E + 255) / 256, 256, 0, stream>>>(dst, deg, E);
  int nblk = (N + 511) / 512;
  scan1_kernel<<<nblk, 512, 0, stream>>>(deg, cursor, bsum, N);
  scan2_kernel<<<1, 512, 0, stream>>>(bsum, nblk);
  scanfix_kernel<<<nblk, 512, 0, stream>>>(cursor, bsum, deg, row_ptr, cursor, N);
  scatter_kernel<<<(E + 255) / 256, 256, 0, stream>>>(src, dst, cursor, col, E);

  const int gb = (N + 127) / 128;
  // ---- layer 1 ----
  gemm128_kernel<<<gb, 256, 0, stream>>>(x, W1, bufA, N);
  el_er_kernel<4, 32><<<(N * 4 + 7) / 8, 256, 0, stream>>>(bufA, al1, ar1, el, er, N);
  aggregate_kernel<4, 32, true><<<(N + 3) / 4, 256, 0, stream>>>(bufA, el, er, b1, row_ptr, col, bufB, N);
  // ---- layer 2 ----
  gemm128_kernel<<<gb, 256, 0, stream>>>(bufB, W2, bufA, N);
  el_er_kernel<4, 32><<<(N * 4 + 7) / 8, 256, 0, stream>>>(bufA, al2, ar2, el, er, N);
  aggregate_kernel<4, 32, true><<<(N + 3) / 4, 256, 0, stream>>>(bufA, el, er, b2, row_ptr, col, bufB, N);
  // ---- layer 3 ----
  gemm_n32_kernel<<<(N + 31) / 32, 256, 0, stream>>>(bufB, W3, bufA, N);
  el_er_kernel<1, 32><<<(N + 7) / 8, 256, 0, stream>>>(bufA, al3, ar3, el, er, N);
  aggregate_kernel<1, 32, false><<<(N + 15) / 16, 256, 0, stream>>>(bufA, el, er, b3, row_ptr, col, out, N);
}